// Round 6
// baseline (536.279 us; speedup 1.0000x reference)
//
#include <hip/hip_runtime.h>

// ---------------------------------------------------------------------------
// RGAT encoder: N=50000, E=800000, R=8, IN=H=128, B=10.
// R6 = R2 dataflow with a fixed xW producer:
//   k_xw  : grid (N/64, 8r) x 256thr, barrier-free, operand-swapped MFMA.
//           A = W^T rows (L1/L2-hot), B = x rows in registers. Lane ends up
//           with 4 consecutive channels -> uint2 repack in wave-private LDS
//           -> dwordx4 coalesced stores. y==0 also emits the score table.
//   k_aggr: R2-proven gather: wave/target, online softmax, 16 lanes/edge,
//           4 dwordx4 loads in flight, single 8-float accumulator (no r logic).
//   k_gemmL: final linear (inline Wl cvt). CSR built once.
// ---------------------------------------------------------------------------

typedef unsigned int uint;
typedef unsigned short ushort_t;

using bf16x8 = __attribute__((ext_vector_type(8))) __bf16;
using f32x4  = __attribute__((ext_vector_type(4))) float;

__device__ __forceinline__ ushort_t fToBf(float f) {
  uint u = __float_as_uint(f);
  u += 0x7FFFu + ((u >> 16) & 1);   // round-to-nearest-even
  return (ushort_t)(u >> 16);
}
__device__ __forceinline__ float bfToF(ushort_t h) {
  return __uint_as_float(((uint)h) << 16);
}

// ------------------------------- CSR build ---------------------------------

__global__ void k_count(const int* __restrict__ tgt, int* __restrict__ deg, int E) {
  int e = blockIdx.x * 256 + threadIdx.x;
  if (e < E) atomicAdd(&deg[tgt[e]], 1);
}

__global__ void k_scanA(const int* __restrict__ deg, int* __restrict__ incl,
                        int* __restrict__ bsum, int n) {
  __shared__ int s[256];
  int tid = threadIdx.x;
  int i = blockIdx.x * 256 + tid;
  int v = (i < n) ? deg[i] : 0;
  s[tid] = v;
  __syncthreads();
  for (int off = 1; off < 256; off <<= 1) {
    int t = (tid >= off) ? s[tid - off] : 0;
    __syncthreads();
    s[tid] += t;
    __syncthreads();
  }
  if (i < n) incl[i] = s[tid];
  if (tid == 255) bsum[blockIdx.x] = s[255];
}

__global__ void k_scanB(int* __restrict__ bsum, int nb) {
  __shared__ int s[256];
  int tid = threadIdx.x;
  int v = (tid < nb) ? bsum[tid] : 0;
  s[tid] = v;
  __syncthreads();
  for (int off = 1; off < 256; off <<= 1) {
    int t = (tid >= off) ? s[tid - off] : 0;
    __syncthreads();
    s[tid] += t;
    __syncthreads();
  }
  if (tid < nb) bsum[tid] = s[tid] - v;   // exclusive
}

__global__ void k_scanC(const int* __restrict__ deg, const int* __restrict__ incl,
                        const int* __restrict__ bsum, int* __restrict__ rowptr,
                        int n, int E) {
  int i = blockIdx.x * 256 + threadIdx.x;
  if (i < n) {
    rowptr[i] = bsum[blockIdx.x] + incl[i] - deg[i];
    if (i == n - 1) rowptr[n] = E;
  }
}

__global__ void k_scatter(const int* __restrict__ src, const int* __restrict__ tgt,
                          const int* __restrict__ et, const int* __restrict__ rowptr,
                          int* __restrict__ cursor, int* __restrict__ sorted, int E) {
  int e = blockIdx.x * 256 + threadIdx.x;
  if (e >= E) return;
  int t = tgt[e];
  int pos = atomicAdd(&cursor[t], 1);
  sorted[rowptr[t] + pos] = src[e] | (et[e] << 16);   // src < 65536, rel < 8
}

// ------------------------------ weight prep --------------------------------

// WT[layer][r][n][k] = W_layer[r][k][n]  (bf16) — A-operand (channel) rows.
__global__ void k_wT(const float* __restrict__ W1, const float* __restrict__ W2,
                     ushort_t* __restrict__ WT) {
  int b = blockIdx.x;                 // layer*1024 + r*128 + n
  const float* W = (b >= 1024) ? W2 : W1;
  int rn = b & 1023;
  int r = rn >> 7, n = rn & 127;
  int k = threadIdx.x;
  WT[(size_t)b * 128 + k] = fToBf(W[((size_t)r * 128 + k) * 128 + n]);
}

// wqk[layer][16][128] bf16: rows 0..7 = Wq[r] = W_r @ q, rows 8..15 = Wk[r].
__global__ void k_wqwk(const float* __restrict__ W1, const float* __restrict__ q1,
                       const float* __restrict__ k1, const float* __restrict__ W2,
                       const float* __restrict__ q2, const float* __restrict__ k2,
                       ushort_t* __restrict__ wqk) {
  int g = blockIdx.x * 256 + threadIdx.x;   // 0..4095
  if (g >= 4096) return;
  int layer = g >> 11;
  int which = (g >> 10) & 1;
  int idx = g & 1023;                        // r*128 + kin
  const float* w = (layer ? W2 : W1) + (size_t)idx * 128;
  const float* v = layer ? (which ? k2 : q2) : (which ? k1 : q1);
  float s = 0.f;
  #pragma unroll 8
  for (int h = 0; h < 128; h++) s += w[h] * v[h];
  int r = idx >> 7, kin = idx & 127;
  wqk[(size_t)layer * 2048 + ((which << 3) + r) * 128 + kin] = fToBf(s);
}

// ------------------------------ xW producer --------------------------------
// grid (ceil(M/64), 8). Block = 4 waves; wave owns 16 nodes x 128 channels of
// relation blockIdx.y. Barrier-free; LDS is wave-private repack space.
// Fragment conventions (R1/R2-verified): A-frag m=lane&15, k=quad*8+j;
// B-frag n=lane&15, k=quad*8+j; C/D row(m)=quad*4+reg, col(n)=lane&15.

template <bool F32IN>
__global__ __launch_bounds__(256, 4) void
k_xw(const void* __restrict__ Ain,          // [M][128] f32 or bf16 node feats
     const ushort_t* __restrict__ WT,       // [8][128][128] this layer
     const ushort_t* __restrict__ Wqk,      // [16][128] this layer
     ushort_t* __restrict__ xW,             // [8][M][128] out
     float* __restrict__ stbl,              // [M][16] out (y==0 only)
     int M) {
  __shared__ __align__(16) ushort_t rp[4][16 * 136];
  int tid = threadIdx.x, wv = tid >> 6, lane = tid & 63;
  int l15 = lane & 15, quad = lane >> 4;
  int nodeBase = blockIdx.x * 64 + wv * 16;
  int r = blockIdx.y;
  ushort_t* rpw = rp[wv];

  int node = nodeBase + l15;
  int nc = node < M ? node : M - 1;

  // B-frags: this lane's node row, all 4 k-blocks (registers for all passes)
  bf16x8 bx[4];
  if (F32IN) {
    const float* row = (const float*)Ain + (size_t)nc * 128;
    #pragma unroll
    for (int kb = 0; kb < 4; kb++) {
      float4 a = *(const float4*)(row + kb * 32 + quad * 8);
      float4 b = *(const float4*)(row + kb * 32 + quad * 8 + 4);
      union { bf16x8 v; ushort_t u[8]; } t;
      t.u[0] = fToBf(a.x); t.u[1] = fToBf(a.y); t.u[2] = fToBf(a.z); t.u[3] = fToBf(a.w);
      t.u[4] = fToBf(b.x); t.u[5] = fToBf(b.y); t.u[6] = fToBf(b.z); t.u[7] = fToBf(b.w);
      bx[kb] = t.v;
    }
  } else {
    const ushort_t* row = (const ushort_t*)Ain + (size_t)nc * 128;
    #pragma unroll
    for (int kb = 0; kb < 4; kb++)
      bx[kb] = *(const bf16x8*)(row + kb * 32 + quad * 8);
  }

  // 8 m-tiles of channels; lane ends with ch mt*16+quad*4+[0..3] of node l15
  const ushort_t* Wr = WT + (size_t)r * 16384;
  #pragma unroll
  for (int mt = 0; mt < 8; mt++) {
    bf16x8 af[4];
    #pragma unroll
    for (int kb = 0; kb < 4; kb++)
      af[kb] = *(const bf16x8*)(Wr + (size_t)(mt * 16 + l15) * 128 + kb * 32 + quad * 8);
    f32x4 acc = {};
    #pragma unroll
    for (int kb = 0; kb < 4; kb++)
      acc = __builtin_amdgcn_mfma_f32_16x16x32_bf16(af[kb], bx[kb], acc, 0, 0, 0);
    uint2 p;
    p.x = (uint)fToBf(acc[0]) | ((uint)fToBf(acc[1]) << 16);
    p.y = (uint)fToBf(acc[2]) | ((uint)fToBf(acc[3]) << 16);
    *(uint2*)(rpw + (size_t)l15 * 136 + mt * 16 + quad * 4) = p;
  }

  // score pass (one relation-block only): stbl[node][0..15]
  if (blockIdx.y == 0) {
    bf16x8 aq[4];
    #pragma unroll
    for (int kb = 0; kb < 4; kb++)
      aq[kb] = *(const bf16x8*)(Wqk + (size_t)l15 * 128 + kb * 32 + quad * 8);
    f32x4 s = {};
    #pragma unroll
    for (int kb = 0; kb < 4; kb++)
      s = __builtin_amdgcn_mfma_f32_16x16x32_bf16(aq[kb], bx[kb], s, 0, 0, 0);
    if (node < M) {
      float4 v = {s[0], s[1], s[2], s[3]};
      *(float4*)(stbl + (size_t)node * 16 + quad * 4) = v;
    }
  }

  // wave-local flush: 16 rows x 256B, coalesced dwordx4 stores
  #pragma unroll
  for (int k = 0; k < 4; k++) {
    int row = k * 4 + quad;
    int4 v = *(const int4*)(rpw + (size_t)row * 136 + l15 * 8);
    int gn = nodeBase + row;
    if (gn < M)
      *(int4*)(xW + ((size_t)r * M + gn) * 128 + l15 * 8) = v;
  }
}

// -------------------- fused softmax + weighted aggregation -----------------
// R2-proven. One wave/target: online softmax; gather 16 lanes/edge (dwordx4),
// 4 edges/group, 4 groups in flight. Epilogue: +bias, relu, bf16 out.

#define ACC8(W_, V_)                                                     \
  acc[0] += W_ * bfToF((ushort_t)(V_.x & 0xFFFF));                       \
  acc[1] += W_ * bfToF((ushort_t)(V_.x >> 16));                          \
  acc[2] += W_ * bfToF((ushort_t)(V_.y & 0xFFFF));                       \
  acc[3] += W_ * bfToF((ushort_t)(V_.y >> 16));                          \
  acc[4] += W_ * bfToF((ushort_t)(V_.z & 0xFFFF));                       \
  acc[5] += W_ * bfToF((ushort_t)(V_.z >> 16));                          \
  acc[6] += W_ * bfToF((ushort_t)(V_.w & 0xFFFF));                       \
  acc[7] += W_ * bfToF((ushort_t)(V_.w >> 16));

__global__ __launch_bounds__(256) void
k_aggr(const ushort_t* __restrict__ feat,   // [R*N][128] bf16 (= xW)
       const float* __restrict__ stbl,      // [N][16]: 0..7 q-side, 8..15 k-side
       const int* __restrict__ rowptr, const int* __restrict__ sorted,
       const float* __restrict__ bias, ushort_t* __restrict__ outp, int n) {
  int tid = threadIdx.x, wv = tid >> 6, lane = tid & 63;
  int t = blockIdx.x * 4 + wv;
  if (t >= n) return;
  int e0 = rowptr[t], e1 = rowptr[t + 1];
  int g4 = lane >> 4, fcol = lane & 15;

  float m = -INFINITY, den = 0.f;
  float acc[8] = {};

  for (int base = e0; base < e1; base += 64) {
    int cnt = min(64, e1 - base);
    float alpha = -INFINITY;
    int pk = 0;
    if (lane < cnt) {
      pk = sorted[base + lane];
      int s = pk & 0xFFFF, r = pk >> 16;
      float a = stbl[(size_t)t * 16 + r] + stbl[(size_t)s * 16 + 8 + r];
      alpha = (a >= 0.f) ? a : 0.2f * a;   // leaky_relu 0.2
    }
    float cm = alpha;
    #pragma unroll
    for (int off = 32; off; off >>= 1) cm = fmaxf(cm, __shfl_xor(cm, off, 64));
    float nm = fmaxf(m, cm);
    float sc = __expf(m - nm);
    den *= sc;
    #pragma unroll
    for (int i = 0; i < 8; i++) acc[i] *= sc;
    float w = (lane < cnt) ? __expf(alpha - nm) : 0.f;
    float ws = w;
    #pragma unroll
    for (int off = 32; off; off >>= 1) ws += __shfl_xor(ws, off, 64);
    den += ws;
    m = nm;

    for (int g = 0; g < cnt; g += 16) {    // 16 edges/iter, 4 dwordx4 in flight
      int i0 = g + g4;
      float w0 = __shfl(w, i0, 64);
      float w1 = __shfl(w, i0 + 4, 64);
      float w2 = __shfl(w, i0 + 8, 64);
      float w3 = __shfl(w, i0 + 12, 64);
      int p0 = __shfl(pk, i0, 64);
      int p1 = __shfl(pk, i0 + 4, 64);
      int p2 = __shfl(pk, i0 + 8, 64);
      int p3 = __shfl(pk, i0 + 12, 64);
      const uint4* r0 = (const uint4*)(feat + (size_t)((p0 >> 16) * n + (p0 & 0xFFFF)) * 128) + fcol;
      const uint4* r1 = (const uint4*)(feat + (size_t)((p1 >> 16) * n + (p1 & 0xFFFF)) * 128) + fcol;
      const uint4* r2 = (const uint4*)(feat + (size_t)((p2 >> 16) * n + (p2 & 0xFFFF)) * 128) + fcol;
      const uint4* r3 = (const uint4*)(feat + (size_t)((p3 >> 16) * n + (p3 & 0xFFFF)) * 128) + fcol;
      uint4 v0 = *r0;
      uint4 v1 = *r1;
      uint4 v2 = *r2;
      uint4 v3 = *r3;
      ACC8(w0, v0)
      ACC8(w1, v1)
      ACC8(w2, v2)
      ACC8(w3, v3)
    }
  }

  #pragma unroll
  for (int i = 0; i < 8; i++) acc[i] += __shfl_xor(acc[i], 16, 64);
  #pragma unroll
  for (int i = 0; i < 8; i++) acc[i] += __shfl_xor(acc[i], 32, 64);

  float inv = (den > 0.f) ? 1.f / (den + 1e-16f) : 0.f;
  uint4 o;
  uint* op = (uint*)&o;
  #pragma unroll
  for (int j = 0; j < 4; j++) {
    float a0 = fmaxf(acc[2 * j] * inv + bias[fcol * 8 + 2 * j], 0.f);
    float a1 = fmaxf(acc[2 * j + 1] * inv + bias[fcol * 8 + 2 * j + 1], 0.f);
    op[j] = (uint)fToBf(a0) | ((uint)fToBf(a1) << 16);
  }
  if (lane < 16) *(uint4*)(outp + (size_t)t * 128 + fcol * 8) = o;
}

// ----------------------------- final linear --------------------------------

#define LDA 136

__global__ __launch_bounds__(256) void
k_gemmL(const ushort_t* __restrict__ A, const float* __restrict__ Wl,
        float* __restrict__ Cout, const float* __restrict__ bias, int M) {
  __shared__ ushort_t As[64 * LDA];
  __shared__ ushort_t Bs[128 * LDA];
  int tid = threadIdx.x;
  int row0 = blockIdx.x * 64;
  for (int c = tid; c < 1024; c += 256) {
    int r = c >> 4, off = (c & 15) * 8;
    int4 v = {0, 0, 0, 0};
    if (row0 + r < M) v = *(const int4*)(A + (size_t)(row0 + r) * 128 + off);
    *(int4*)(As + r * LDA + off) = v;
  }
  for (int c = tid; c < 2048; c += 256) {
    int nn = c >> 4, off = (c & 15) * 8;
    float4 a = *(const float4*)(Wl + (size_t)nn * 128 + off);
    float4 b = *(const float4*)(Wl + (size_t)nn * 128 + off + 4);
    ushort_t* d = Bs + nn * LDA + off;
    d[0] = fToBf(a.x); d[1] = fToBf(a.y); d[2] = fToBf(a.z); d[3] = fToBf(a.w);
    d[4] = fToBf(b.x); d[5] = fToBf(b.y); d[6] = fToBf(b.z); d[7] = fToBf(b.w);
  }
  __syncthreads();
  int wv = tid >> 6, lane = tid & 63;
  int l15 = lane & 15, quad = lane >> 4;
  int wr = wv * 16;
  bf16x8 afr[4];
  #pragma unroll
  for (int kb = 0; kb < 4; kb++)
    afr[kb] = *reinterpret_cast<const bf16x8*>(As + (wr + l15) * LDA + kb * 32 + quad * 8);
  f32x4 acc[8] = {};
  #pragma unroll
  for (int ct = 0; ct < 8; ct++)
    #pragma unroll
    for (int kb = 0; kb < 4; kb++) {
      bf16x8 bfr = *reinterpret_cast<const bf16x8*>(Bs + (ct * 16 + l15) * LDA + kb * 32 + quad * 8);
      acc[ct] = __builtin_amdgcn_mfma_f32_16x16x32_bf16(afr[kb], bfr, acc[ct], 0, 0, 0);
    }
  #pragma unroll
  for (int ct = 0; ct < 8; ct++)
    #pragma unroll
    for (int reg = 0; reg < 4; reg++) {
      int rr = row0 + wr + quad * 4 + reg;
      if (rr < M) Cout[(size_t)rr * 128 + ct * 16 + l15] = acc[ct][reg] + bias[ct * 16 + l15];
    }
}

// ------------------------------- launcher ----------------------------------

extern "C" void kernel_launch(void* const* d_in, const int* in_sizes, int n_in,
                              void* d_out, int out_size, void* d_ws, size_t ws_size,
                              hipStream_t stream) {
  const float* x   = (const float*)d_in[0];
  const int* ei    = (const int*)d_in[1];
  const int* etype = (const int*)d_in[2];
  const float* W1  = (const float*)d_in[4];
  const float* q1  = (const float*)d_in[5];
  const float* k1  = (const float*)d_in[6];
  const float* b1  = (const float*)d_in[7];
  const float* W2  = (const float*)d_in[8];
  const float* q2  = (const float*)d_in[9];
  const float* k2  = (const float*)d_in[10];
  const float* b2  = (const float*)d_in[11];
  const float* Wl  = (const float*)d_in[12];
  const float* bl  = (const float*)d_in[13];
  float* out       = (float*)d_out;

  const int N = in_sizes[0] / 128;   // 50000
  const int E = in_sizes[2];         // 800000

  char* ws = (char*)d_ws;
  size_t off = 0;
  auto alloc = [&](size_t bytes) {
    size_t o = off;
    off = (off + bytes + 255) & ~(size_t)255;
    return o;
  };

  ushort_t* xW    = (ushort_t*)(ws + alloc((size_t)8 * N * 128 * 2));
  ushort_t* h1    = (ushort_t*)(ws + alloc((size_t)N * 128 * 2));
  ushort_t* h2    = (ushort_t*)(ws + alloc((size_t)N * 128 * 2));
  ushort_t* wT    = (ushort_t*)(ws + alloc((size_t)2 * 8 * 128 * 128 * 2));
  ushort_t* wqk   = (ushort_t*)(ws + alloc(2 * 16 * 128 * 2));
  float* stblA    = (float*)(ws + alloc((size_t)N * 16 * 4));
  float* stblB    = (float*)(ws + alloc((size_t)N * 16 * 4));
  int* deg        = (int*)(ws + alloc((size_t)N * 4));
  int* cursor     = (int*)(ws + alloc((size_t)N * 4));
  int* incl       = (int*)(ws + alloc((size_t)N * 4));
  int* rowptr     = (int*)(ws + alloc((size_t)(N + 1) * 4));
  int* bsum       = (int*)(ws + alloc(256 * 4));
  int* sorted     = (int*)(ws + alloc((size_t)E * 4));
  (void)ws_size; (void)n_in; (void)out_size;

  const int* srcp = ei;
  const int* tgtp = ei + E;

  int gE = (E + 255) / 256;
  int gN = (N + 255) / 256;
  int gW = (N + 3) / 4;         // k_aggr
  int gX = (N + 63) / 64;       // k_xw / k_gemmL: 782

  // CSR build (once; same graph both layers)
  hipMemsetAsync(deg, 0, (size_t)N * 4, stream);
  hipMemsetAsync(cursor, 0, (size_t)N * 4, stream);
  k_count<<<gE, 256, 0, stream>>>(tgtp, deg, E);
  k_scanA<<<gN, 256, 0, stream>>>(deg, incl, bsum, N);
  k_scanB<<<1, 256, 0, stream>>>(bsum, gN);
  k_scanC<<<gN, 256, 0, stream>>>(deg, incl, bsum, rowptr, N, E);
  k_scatter<<<gE, 256, 0, stream>>>(srcp, tgtp, etype, rowptr, cursor, sorted, E);

  // weight prep (both layers)
  k_wT<<<2048, 128, 0, stream>>>(W1, W2, wT);
  k_wqwk<<<16, 256, 0, stream>>>(W1, q1, k1, W2, q2, k2, wqk);

  // layer 1 (reads f32 x directly; emits xW + stblA)
  k_xw<true><<<dim3(gX, 8), 256, 0, stream>>>(x, wT, wqk, xW, stblA, N);
  k_aggr<<<gW, 256, 0, stream>>>(xW, stblA, rowptr, sorted, b1, h1, N);

  // layer 2
  k_xw<false><<<dim3(gX, 8), 256, 0, stream>>>(h1, wT + (size_t)8 * 128 * 128,
                                               wqk + 2048, xW, stblB, N);
  k_aggr<<<gW, 256, 0, stream>>>(xW, stblB, rowptr, sorted, b2, h2, N);

  // final linear
  k_gemmL<<<gX, 256, 0, stream>>>(h2, Wl, out, bl, N);
}

// Round 7
// 504.121 us; speedup vs baseline: 1.0638x; 1.0638x over previous
//
#include <hip/hip_runtime.h>

// ---------------------------------------------------------------------------
// RGAT encoder: N=50000, E=800000, R=8, IN=H=128, B=10.
// R7: R2 dataflow; xW producer rebuilt on three measured lessons:
//   - x is read ONCE (block = 64 nodes x ALL 8 relations; x-frags in regs)
//   - W comes from LDS in precomputed MFMA-fragment order (k_wTf) ->
//     staging is a flat 32 KB copy, ds_read_b128 lane-sequential (0 conflicts),
//     double-buffered, 1 barrier/relation
//   - operand-swapped D => lane holds 4 consecutive channels => direct 8 B
//     global stores (no repack LDS)
// k_aggr: R2-proven gather (wave/target, online softmax, 16 lanes/edge,
//         4 dwordx4 in flight). k_gemmL: final linear. CSR built once.
// ---------------------------------------------------------------------------

typedef unsigned int uint;
typedef unsigned short ushort_t;

using bf16x8 = __attribute__((ext_vector_type(8))) __bf16;
using f32x4  = __attribute__((ext_vector_type(4))) float;

__device__ __forceinline__ ushort_t fToBf(float f) {
  uint u = __float_as_uint(f);
  u += 0x7FFFu + ((u >> 16) & 1);   // round-to-nearest-even
  return (ushort_t)(u >> 16);
}
__device__ __forceinline__ float bfToF(ushort_t h) {
  return __uint_as_float(((uint)h) << 16);
}

// ------------------------------- CSR build ---------------------------------

__global__ void k_count(const int* __restrict__ tgt, int* __restrict__ deg, int E) {
  int e = blockIdx.x * 256 + threadIdx.x;
  if (e < E) atomicAdd(&deg[tgt[e]], 1);
}

__global__ void k_scanA(const int* __restrict__ deg, int* __restrict__ incl,
                        int* __restrict__ bsum, int n) {
  __shared__ int s[256];
  int tid = threadIdx.x;
  int i = blockIdx.x * 256 + tid;
  int v = (i < n) ? deg[i] : 0;
  s[tid] = v;
  __syncthreads();
  for (int off = 1; off < 256; off <<= 1) {
    int t = (tid >= off) ? s[tid - off] : 0;
    __syncthreads();
    s[tid] += t;
    __syncthreads();
  }
  if (i < n) incl[i] = s[tid];
  if (tid == 255) bsum[blockIdx.x] = s[255];
}

__global__ void k_scanB(int* __restrict__ bsum, int nb) {
  __shared__ int s[256];
  int tid = threadIdx.x;
  int v = (tid < nb) ? bsum[tid] : 0;
  s[tid] = v;
  __syncthreads();
  for (int off = 1; off < 256; off <<= 1) {
    int t = (tid >= off) ? s[tid - off] : 0;
    __syncthreads();
    s[tid] += t;
    __syncthreads();
  }
  if (tid < nb) bsum[tid] = s[tid] - v;   // exclusive
}

__global__ void k_scanC(const int* __restrict__ deg, const int* __restrict__ incl,
                        const int* __restrict__ bsum, int* __restrict__ rowptr,
                        int n, int E) {
  int i = blockIdx.x * 256 + threadIdx.x;
  if (i < n) {
    rowptr[i] = bsum[blockIdx.x] + incl[i] - deg[i];
    if (i == n - 1) rowptr[n] = E;
  }
}

__global__ void k_scatter(const int* __restrict__ src, const int* __restrict__ tgt,
                          const int* __restrict__ et, const int* __restrict__ rowptr,
                          int* __restrict__ cursor, int* __restrict__ sorted, int E) {
  int e = blockIdx.x * 256 + threadIdx.x;
  if (e >= E) return;
  int t = tgt[e];
  int pos = atomicAdd(&cursor[t], 1);
  sorted[rowptr[t] + pos] = src[e] | (et[e] << 16);   // src < 65536, rel < 8
}

// ------------------------------ weight prep --------------------------------
// WTf[layer][r][f=mt*4+kb][lane][j] = W[r][kb*32+(lane>>4)*8+j][mt*16+(lane&15)]
// i.e. the A-operand fragment each lane needs, laid out so a wave's
// ds_read_b128 is perfectly lane-sequential. 32 KB per (layer, r).

__global__ void k_wTf(const float* __restrict__ W1, const float* __restrict__ W2,
                      ushort_t* __restrict__ WTf) {
  int b = blockIdx.x * 4 + (threadIdx.x >> 6);   // layer*256 + r*32 + f
  int lane = threadIdx.x & 63;
  int layer = b >> 8;
  int r = (b >> 5) & 7;
  int f = b & 31;
  int mt = f >> 2, kb = f & 3;
  const float* W = layer ? W2 : W1;
  int col = mt * 16 + (lane & 15);
  int krow = kb * 32 + (lane >> 4) * 8;
  ushort_t* dst = WTf + ((size_t)b * 64 + lane) * 8;
  #pragma unroll
  for (int j = 0; j < 8; j++)
    dst[j] = fToBf(W[((size_t)r * 128 + krow + j) * 128 + col]);
}

// wqk[layer][16][128] bf16: rows 0..7 = Wq[r] = W_r @ q, rows 8..15 = Wk[r].
__global__ void k_wqwk(const float* __restrict__ W1, const float* __restrict__ q1,
                       const float* __restrict__ k1, const float* __restrict__ W2,
                       const float* __restrict__ q2, const float* __restrict__ k2,
                       ushort_t* __restrict__ wqk) {
  int g = blockIdx.x * 256 + threadIdx.x;   // 0..4095
  if (g >= 4096) return;
  int layer = g >> 11;
  int which = (g >> 10) & 1;
  int idx = g & 1023;                        // r*128 + kin
  const float* w = (layer ? W2 : W1) + (size_t)idx * 128;
  const float* v = layer ? (which ? k2 : q2) : (which ? k1 : q1);
  float s = 0.f;
  #pragma unroll 8
  for (int h = 0; h < 128; h++) s += w[h] * v[h];
  int r = idx >> 7, kin = idx & 127;
  wqk[(size_t)layer * 2048 + ((which << 3) + r) * 128 + kin] = fToBf(s);
}

// ------------------------------ xW producer --------------------------------
// Block = 256 thr = 4 waves = 64 nodes; loops ALL 8 relations (x read once).
// W[r] staged as flat 32 KB fragment-order copy, double-buffered; one barrier
// per relation. MFMA operand-swapped: A = W channel rows (LDS), B = x node
// rows (regs). D row = channel -> lane owns 4 consecutive channels of one
// node -> direct uint2 stores. Also emits the score table (wqk from L2).
// Fragment conventions (R1/R2-verified): A-frag m=lane&15, k=quad*8+j;
// B-frag n=lane&15, k=quad*8+j; C/D row(m)=quad*4+reg, col(n)=lane&15.

template <bool F32IN>
__global__ __launch_bounds__(256) void
k_xw(const void* __restrict__ Ain,          // [M][128] f32 or bf16 node feats
     const ushort_t* __restrict__ WTf,      // [8][32][64][8] this layer
     const ushort_t* __restrict__ Wqk,      // [16][128] this layer
     ushort_t* __restrict__ xW,             // [8][M][128] out
     float* __restrict__ stbl,              // [M][16] out
     int M) {
  __shared__ __align__(16) ushort_t wbuf[2][16384];   // 2 x 32 KB
  int tid = threadIdx.x, wv = tid >> 6, lane = tid & 63;
  int l15 = lane & 15, quad = lane >> 4;
  int node0 = blockIdx.x * 64 + wv * 16;
  int node = node0 + l15;
  int nc = node < M ? node : M - 1;

  // B-frags: this lane's node row (registers for all 8 relations + scores)
  bf16x8 bx[4];
  if (F32IN) {
    const float* row = (const float*)Ain + (size_t)nc * 128;
    #pragma unroll
    for (int kb = 0; kb < 4; kb++) {
      float4 a = *(const float4*)(row + kb * 32 + quad * 8);
      float4 b = *(const float4*)(row + kb * 32 + quad * 8 + 4);
      union { bf16x8 v; ushort_t u[8]; } t;
      t.u[0] = fToBf(a.x); t.u[1] = fToBf(a.y); t.u[2] = fToBf(a.z); t.u[3] = fToBf(a.w);
      t.u[4] = fToBf(b.x); t.u[5] = fToBf(b.y); t.u[6] = fToBf(b.z); t.u[7] = fToBf(b.w);
      bx[kb] = t.v;
    }
  } else {
    const ushort_t* row = (const ushort_t*)Ain + (size_t)nc * 128;
    #pragma unroll
    for (int kb = 0; kb < 4; kb++)
      bx[kb] = *(const bf16x8*)(row + kb * 32 + quad * 8);
  }

  // stage W[0]
  #pragma unroll
  for (int i = 0; i < 8; i++)
    *(int4*)(wbuf[0] + (size_t)(tid + i * 256) * 8) =
        *(const int4*)(WTf + (size_t)(tid + i * 256) * 8);
  __syncthreads();

  for (int r = 0; r < 8; r++) {
    // prefetch W[r+1] into registers (hidden behind compute)
    int4 pf[8];
    if (r < 7) {
      const ushort_t* src = WTf + (size_t)(r + 1) * 16384;
      #pragma unroll
      for (int i = 0; i < 8; i++)
        pf[i] = *(const int4*)(src + (size_t)(tid + i * 256) * 8);
    }
    // compute from wbuf[r&1]: 8 channel tiles x 4 k-blocks
    const ushort_t* wb = wbuf[r & 1];
    #pragma unroll
    for (int mt = 0; mt < 8; mt++) {
      f32x4 acc = {};
      #pragma unroll
      for (int kb = 0; kb < 4; kb++) {
        bf16x8 af = *(const bf16x8*)(wb + (size_t)((mt * 4 + kb) * 64 + lane) * 8);
        acc = __builtin_amdgcn_mfma_f32_16x16x32_bf16(af, bx[kb], acc, 0, 0, 0);
      }
      if (node < M) {
        uint2 p;
        p.x = (uint)fToBf(acc[0]) | ((uint)fToBf(acc[1]) << 16);
        p.y = (uint)fToBf(acc[2]) | ((uint)fToBf(acc[3]) << 16);
        *(uint2*)(xW + ((size_t)r * M + node) * 128 + mt * 16 + quad * 4) = p;
      }
    }
    // write prefetched W[r+1] into the other buffer
    if (r < 7) {
      ushort_t* db = wbuf[(r + 1) & 1];
      #pragma unroll
      for (int i = 0; i < 8; i++)
        *(int4*)(db + (size_t)(tid + i * 256) * 8) = pf[i];
    }
    __syncthreads();
  }

  // score pass: stbl[node][0..7] = x.Wq[r], [8..15] = x.Wk[r]
  bf16x8 aq[4];
  #pragma unroll
  for (int kb = 0; kb < 4; kb++)
    aq[kb] = *(const bf16x8*)(Wqk + (size_t)l15 * 128 + kb * 32 + quad * 8);
  f32x4 s = {};
  #pragma unroll
  for (int kb = 0; kb < 4; kb++)
    s = __builtin_amdgcn_mfma_f32_16x16x32_bf16(aq[kb], bx[kb], s, 0, 0, 0);
  if (node < M) {
    float4 v = {s[0], s[1], s[2], s[3]};
    *(float4*)(stbl + (size_t)node * 16 + quad * 4) = v;
  }
}

// -------------------- fused softmax + weighted aggregation -----------------
// R2-proven. One wave/target: online softmax; gather 16 lanes/edge (dwordx4),
// 4 edges/group, 4 groups in flight. Epilogue: +bias, relu, bf16 out.

#define ACC8(W_, V_)                                                     \
  acc[0] += W_ * bfToF((ushort_t)(V_.x & 0xFFFF));                       \
  acc[1] += W_ * bfToF((ushort_t)(V_.x >> 16));                          \
  acc[2] += W_ * bfToF((ushort_t)(V_.y & 0xFFFF));                       \
  acc[3] += W_ * bfToF((ushort_t)(V_.y >> 16));                          \
  acc[4] += W_ * bfToF((ushort_t)(V_.z & 0xFFFF));                       \
  acc[5] += W_ * bfToF((ushort_t)(V_.z >> 16));                          \
  acc[6] += W_ * bfToF((ushort_t)(V_.w & 0xFFFF));                       \
  acc[7] += W_ * bfToF((ushort_t)(V_.w >> 16));

__global__ __launch_bounds__(256) void
k_aggr(const ushort_t* __restrict__ feat,   // [R*N][128] bf16 (= xW)
       const float* __restrict__ stbl,      // [N][16]: 0..7 q-side, 8..15 k-side
       const int* __restrict__ rowptr, const int* __restrict__ sorted,
       const float* __restrict__ bias, ushort_t* __restrict__ outp, int n) {
  int tid = threadIdx.x, wv = tid >> 6, lane = tid & 63;
  int t = blockIdx.x * 4 + wv;
  if (t >= n) return;
  int e0 = rowptr[t], e1 = rowptr[t + 1];
  int g4 = lane >> 4, fcol = lane & 15;

  float m = -INFINITY, den = 0.f;
  float acc[8] = {};

  for (int base = e0; base < e1; base += 64) {
    int cnt = min(64, e1 - base);
    float alpha = -INFINITY;
    int pk = 0;
    if (lane < cnt) {
      pk = sorted[base + lane];
      int s = pk & 0xFFFF, r = pk >> 16;
      float a = stbl[(size_t)t * 16 + r] + stbl[(size_t)s * 16 + 8 + r];
      alpha = (a >= 0.f) ? a : 0.2f * a;   // leaky_relu 0.2
    }
    float cm = alpha;
    #pragma unroll
    for (int off = 32; off; off >>= 1) cm = fmaxf(cm, __shfl_xor(cm, off, 64));
    float nm = fmaxf(m, cm);
    float sc = __expf(m - nm);
    den *= sc;
    #pragma unroll
    for (int i = 0; i < 8; i++) acc[i] *= sc;
    float w = (lane < cnt) ? __expf(alpha - nm) : 0.f;
    float ws = w;
    #pragma unroll
    for (int off = 32; off; off >>= 1) ws += __shfl_xor(ws, off, 64);
    den += ws;
    m = nm;

    for (int g = 0; g < cnt; g += 16) {    // 16 edges/iter, 4 dwordx4 in flight
      int i0 = g + g4;
      float w0 = __shfl(w, i0, 64);
      float w1 = __shfl(w, i0 + 4, 64);
      float w2 = __shfl(w, i0 + 8, 64);
      float w3 = __shfl(w, i0 + 12, 64);
      int p0 = __shfl(pk, i0, 64);
      int p1 = __shfl(pk, i0 + 4, 64);
      int p2 = __shfl(pk, i0 + 8, 64);
      int p3 = __shfl(pk, i0 + 12, 64);
      const uint4* r0 = (const uint4*)(feat + (size_t)((p0 >> 16) * n + (p0 & 0xFFFF)) * 128) + fcol;
      const uint4* r1 = (const uint4*)(feat + (size_t)((p1 >> 16) * n + (p1 & 0xFFFF)) * 128) + fcol;
      const uint4* r2 = (const uint4*)(feat + (size_t)((p2 >> 16) * n + (p2 & 0xFFFF)) * 128) + fcol;
      const uint4* r3 = (const uint4*)(feat + (size_t)((p3 >> 16) * n + (p3 & 0xFFFF)) * 128) + fcol;
      uint4 v0 = *r0;
      uint4 v1 = *r1;
      uint4 v2 = *r2;
      uint4 v3 = *r3;
      ACC8(w0, v0)
      ACC8(w1, v1)
      ACC8(w2, v2)
      ACC8(w3, v3)
    }
  }

  #pragma unroll
  for (int i = 0; i < 8; i++) acc[i] += __shfl_xor(acc[i], 16, 64);
  #pragma unroll
  for (int i = 0; i < 8; i++) acc[i] += __shfl_xor(acc[i], 32, 64);

  float inv = (den > 0.f) ? 1.f / (den + 1e-16f) : 0.f;
  uint4 o;
  uint* op = (uint*)&o;
  #pragma unroll
  for (int j = 0; j < 4; j++) {
    float a0 = fmaxf(acc[2 * j] * inv + bias[fcol * 8 + 2 * j], 0.f);
    float a1 = fmaxf(acc[2 * j + 1] * inv + bias[fcol * 8 + 2 * j + 1], 0.f);
    op[j] = (uint)fToBf(a0) | ((uint)fToBf(a1) << 16);
  }
  if (lane < 16) *(uint4*)(outp + (size_t)t * 128 + fcol * 8) = o;
}

// ----------------------------- final linear --------------------------------

#define LDA 136

__global__ __launch_bounds__(256) void
k_gemmL(const ushort_t* __restrict__ A, const float* __restrict__ Wl,
        float* __restrict__ Cout, const float* __restrict__ bias, int M) {
  __shared__ ushort_t As[64 * LDA];
  __shared__ ushort_t Bs[128 * LDA];
  int tid = threadIdx.x;
  int row0 = blockIdx.x * 64;
  for (int c = tid; c < 1024; c += 256) {
    int r = c >> 4, off = (c & 15) * 8;
    int4 v = {0, 0, 0, 0};
    if (row0 + r < M) v = *(const int4*)(A + (size_t)(row0 + r) * 128 + off);
    *(int4*)(As + r * LDA + off) = v;
  }
  for (int c = tid; c < 2048; c += 256) {
    int nn = c >> 4, off = (c & 15) * 8;
    float4 a = *(const float4*)(Wl + (size_t)nn * 128 + off);
    float4 b = *(const float4*)(Wl + (size_t)nn * 128 + off + 4);
    ushort_t* d = Bs + nn * LDA + off;
    d[0] = fToBf(a.x); d[1] = fToBf(a.y); d[2] = fToBf(a.z); d[3] = fToBf(a.w);
    d[4] = fToBf(b.x); d[5] = fToBf(b.y); d[6] = fToBf(b.z); d[7] = fToBf(b.w);
  }
  __syncthreads();
  int wv = tid >> 6, lane = tid & 63;
  int l15 = lane & 15, quad = lane >> 4;
  int wr = wv * 16;
  bf16x8 afr[4];
  #pragma unroll
  for (int kb = 0; kb < 4; kb++)
    afr[kb] = *reinterpret_cast<const bf16x8*>(As + (wr + l15) * LDA + kb * 32 + quad * 8);
  f32x4 acc[8] = {};
  #pragma unroll
  for (int ct = 0; ct < 8; ct++)
    #pragma unroll
    for (int kb = 0; kb < 4; kb++) {
      bf16x8 bfr = *reinterpret_cast<const bf16x8*>(Bs + (ct * 16 + l15) * LDA + kb * 32 + quad * 8);
      acc[ct] = __builtin_amdgcn_mfma_f32_16x16x32_bf16(afr[kb], bfr, acc[ct], 0, 0, 0);
    }
  #pragma unroll
  for (int ct = 0; ct < 8; ct++)
    #pragma unroll
    for (int reg = 0; reg < 4; reg++) {
      int rr = row0 + wr + quad * 4 + reg;
      if (rr < M) Cout[(size_t)rr * 128 + ct * 16 + l15] = acc[ct][reg] + bias[ct * 16 + l15];
    }
}

// ------------------------------- launcher ----------------------------------

extern "C" void kernel_launch(void* const* d_in, const int* in_sizes, int n_in,
                              void* d_out, int out_size, void* d_ws, size_t ws_size,
                              hipStream_t stream) {
  const float* x   = (const float*)d_in[0];
  const int* ei    = (const int*)d_in[1];
  const int* etype = (const int*)d_in[2];
  const float* W1  = (const float*)d_in[4];
  const float* q1  = (const float*)d_in[5];
  const float* k1  = (const float*)d_in[6];
  const float* b1  = (const float*)d_in[7];
  const float* W2  = (const float*)d_in[8];
  const float* q2  = (const float*)d_in[9];
  const float* k2  = (const float*)d_in[10];
  const float* b2  = (const float*)d_in[11];
  const float* Wl  = (const float*)d_in[12];
  const float* bl  = (const float*)d_in[13];
  float* out       = (float*)d_out;

  const int N = in_sizes[0] / 128;   // 50000
  const int E = in_sizes[2];         // 800000

  char* ws = (char*)d_ws;
  size_t off = 0;
  auto alloc = [&](size_t bytes) {
    size_t o = off;
    off = (off + bytes + 255) & ~(size_t)255;
    return o;
  };

  ushort_t* xW    = (ushort_t*)(ws + alloc((size_t)8 * N * 128 * 2));
  ushort_t* h1    = (ushort_t*)(ws + alloc((size_t)N * 128 * 2));
  ushort_t* h2    = (ushort_t*)(ws + alloc((size_t)N * 128 * 2));
  ushort_t* WTf   = (ushort_t*)(ws + alloc((size_t)2 * 8 * 16384 * 2));
  ushort_t* wqk   = (ushort_t*)(ws + alloc(2 * 16 * 128 * 2));
  float* stblA    = (float*)(ws + alloc((size_t)N * 16 * 4));
  float* stblB    = (float*)(ws + alloc((size_t)N * 16 * 4));
  int* deg        = (int*)(ws + alloc((size_t)N * 4));
  int* cursor     = (int*)(ws + alloc((size_t)N * 4));
  int* incl       = (int*)(ws + alloc((size_t)N * 4));
  int* rowptr     = (int*)(ws + alloc((size_t)(N + 1) * 4));
  int* bsum       = (int*)(ws + alloc(256 * 4));
  int* sorted     = (int*)(ws + alloc((size_t)E * 4));
  (void)ws_size; (void)n_in; (void)out_size;

  const int* srcp = ei;
  const int* tgtp = ei + E;

  int gE = (E + 255) / 256;
  int gN = (N + 255) / 256;
  int gW = (N + 3) / 4;         // k_aggr
  int gX = (N + 63) / 64;       // k_xw / k_gemmL: 782

  // CSR build (once; same graph both layers)
  hipMemsetAsync(deg, 0, (size_t)N * 4, stream);
  hipMemsetAsync(cursor, 0, (size_t)N * 4, stream);
  k_count<<<gE, 256, 0, stream>>>(tgtp, deg, E);
  k_scanA<<<gN, 256, 0, stream>>>(deg, incl, bsum, N);
  k_scanB<<<1, 256, 0, stream>>>(bsum, gN);
  k_scanC<<<gN, 256, 0, stream>>>(deg, incl, bsum, rowptr, N, E);
  k_scatter<<<gE, 256, 0, stream>>>(srcp, tgtp, etype, rowptr, cursor, sorted, E);

  // weight prep (both layers)
  k_wTf<<<128, 256, 0, stream>>>(W1, W2, WTf);
  k_wqwk<<<16, 256, 0, stream>>>(W1, q1, k1, W2, q2, k2, wqk);

  // layer 1 (reads f32 x directly; emits xW + stblA)
  k_xw<true><<<gX, 256, 0, stream>>>(x, WTf, wqk, xW, stblA, N);
  k_aggr<<<gW, 256, 0, stream>>>(xW, stblA, rowptr, sorted, b1, h1, N);

  // layer 2
  k_xw<false><<<gX, 256, 0, stream>>>(h1, WTf + (size_t)8 * 16384,
                                      wqk + 2048, xW, stblB, N);
  k_aggr<<<gW, 256, 0, stream>>>(xW, stblB, rowptr, sorted, b2, h2, N);

  // final linear
  k_gemmL<<<gX, 256, 0, stream>>>(h2, Wl, out, bl, N);
}

// Round 8
// 401.527 us; speedup vs baseline: 1.3356x; 1.2555x over previous
//
#include <hip/hip_runtime.h>

// ---------------------------------------------------------------------------
// RGAT encoder: N=50000, E=800000, R=8, IN=H=128, B=10.
// R8: R7 fetch path (x read once, W double-buffered in LDS in fragment order)
//     + fixed store path: all-mt accumulators kept in registers, xW rows
//     stored in PERMUTED channel order (pos = quad*32+mt*4+j for channel
//     c = mt*16+quad*4+j) so each lane writes 64 contiguous bytes of one
//     row -> dense line coverage, no write amplification, no repack LDS.
// k_aggr: gather is position-agnostic; epilogue un-permutes via bias index
//     and writes h in standard order. k_gemmL unchanged. CSR built once.
// ---------------------------------------------------------------------------

typedef unsigned int uint;
typedef unsigned short ushort_t;

using bf16x8 = __attribute__((ext_vector_type(8))) __bf16;
using f32x4  = __attribute__((ext_vector_type(4))) float;

__device__ __forceinline__ ushort_t fToBf(float f) {
  uint u = __float_as_uint(f);
  u += 0x7FFFu + ((u >> 16) & 1);   // round-to-nearest-even
  return (ushort_t)(u >> 16);
}
__device__ __forceinline__ float bfToF(ushort_t h) {
  return __uint_as_float(((uint)h) << 16);
}
__device__ __forceinline__ uint packBf(float a, float b) {
  return (uint)fToBf(a) | ((uint)fToBf(b) << 16);
}

// ------------------------------- CSR build ---------------------------------

__global__ void k_count(const int* __restrict__ tgt, int* __restrict__ deg, int E) {
  int e = blockIdx.x * 256 + threadIdx.x;
  if (e < E) atomicAdd(&deg[tgt[e]], 1);
}

__global__ void k_scanA(const int* __restrict__ deg, int* __restrict__ incl,
                        int* __restrict__ bsum, int n) {
  __shared__ int s[256];
  int tid = threadIdx.x;
  int i = blockIdx.x * 256 + tid;
  int v = (i < n) ? deg[i] : 0;
  s[tid] = v;
  __syncthreads();
  for (int off = 1; off < 256; off <<= 1) {
    int t = (tid >= off) ? s[tid - off] : 0;
    __syncthreads();
    s[tid] += t;
    __syncthreads();
  }
  if (i < n) incl[i] = s[tid];
  if (tid == 255) bsum[blockIdx.x] = s[255];
}

__global__ void k_scanB(int* __restrict__ bsum, int nb) {
  __shared__ int s[256];
  int tid = threadIdx.x;
  int v = (tid < nb) ? bsum[tid] : 0;
  s[tid] = v;
  __syncthreads();
  for (int off = 1; off < 256; off <<= 1) {
    int t = (tid >= off) ? s[tid - off] : 0;
    __syncthreads();
    s[tid] += t;
    __syncthreads();
  }
  if (tid < nb) bsum[tid] = s[tid] - v;   // exclusive
}

__global__ void k_scanC(const int* __restrict__ deg, const int* __restrict__ incl,
                        const int* __restrict__ bsum, int* __restrict__ rowptr,
                        int n, int E) {
  int i = blockIdx.x * 256 + threadIdx.x;
  if (i < n) {
    rowptr[i] = bsum[blockIdx.x] + incl[i] - deg[i];
    if (i == n - 1) rowptr[n] = E;
  }
}

__global__ void k_scatter(const int* __restrict__ src, const int* __restrict__ tgt,
                          const int* __restrict__ et, const int* __restrict__ rowptr,
                          int* __restrict__ cursor, int* __restrict__ sorted, int E) {
  int e = blockIdx.x * 256 + threadIdx.x;
  if (e >= E) return;
  int t = tgt[e];
  int pos = atomicAdd(&cursor[t], 1);
  sorted[rowptr[t] + pos] = src[e] | (et[e] << 16);   // src < 65536, rel < 8
}

// ------------------------------ weight prep --------------------------------
// WTf[layer][r][f=mt*4+kb][lane][j] = W[r][kb*32+(lane>>4)*8+j][mt*16+(lane&15)]
// A-operand fragments in the exact order waves read them (flat 32 KB/relation).

__global__ void k_wTf(const float* __restrict__ W1, const float* __restrict__ W2,
                      ushort_t* __restrict__ WTf) {
  int b = blockIdx.x * 4 + (threadIdx.x >> 6);   // layer*256 + r*32 + f
  int lane = threadIdx.x & 63;
  int layer = b >> 8;
  int r = (b >> 5) & 7;
  int f = b & 31;
  int mt = f >> 2, kb = f & 3;
  const float* W = layer ? W2 : W1;
  int col = mt * 16 + (lane & 15);
  int krow = kb * 32 + (lane >> 4) * 8;
  ushort_t* dst = WTf + ((size_t)b * 64 + lane) * 8;
  #pragma unroll
  for (int j = 0; j < 8; j++)
    dst[j] = fToBf(W[((size_t)r * 128 + krow + j) * 128 + col]);
}

// wqk[layer][16][128] bf16: rows 0..7 = Wq[r] = W_r @ q, rows 8..15 = Wk[r].
__global__ void k_wqwk(const float* __restrict__ W1, const float* __restrict__ q1,
                       const float* __restrict__ k1, const float* __restrict__ W2,
                       const float* __restrict__ q2, const float* __restrict__ k2,
                       ushort_t* __restrict__ wqk) {
  int g = blockIdx.x * 256 + threadIdx.x;   // 0..4095
  if (g >= 4096) return;
  int layer = g >> 11;
  int which = (g >> 10) & 1;
  int idx = g & 1023;                        // r*128 + kin
  const float* w = (layer ? W2 : W1) + (size_t)idx * 128;
  const float* v = layer ? (which ? k2 : q2) : (which ? k1 : q1);
  float s = 0.f;
  #pragma unroll 8
  for (int h = 0; h < 128; h++) s += w[h] * v[h];
  int r = idx >> 7, kin = idx & 127;
  wqk[(size_t)layer * 2048 + ((which << 3) + r) * 128 + kin] = fToBf(s);
}

// ------------------------------ xW producer --------------------------------
// Block = 256 thr = 4 waves = 128 nodes (32/wave, 2 tiles). Loops all 8
// relations; x-frags in regs (read once); W[r] double-buffered 32 KB LDS
// fragment-order copies (1 barrier/relation, prefetch via regs). All 8 mt
// accumulators packed to bf16 in regs; stores are 4 dwordx4 per tile of
// 64 contiguous bytes per lane (permuted channel order, dense lines).
// Fragment conventions (R1/R2-verified): A-frag m=lane&15, k=quad*8+j;
// B-frag n=lane&15, k=quad*8+j; C/D row(m)=quad*4+reg, col(n)=lane&15.

template <bool F32IN>
__global__ __launch_bounds__(256, 2) void
k_xw(const void* __restrict__ Ain,          // [M][128] f32 or bf16 node feats
     const ushort_t* __restrict__ WTf,      // [8][32][64][8] this layer
     const ushort_t* __restrict__ Wqk,      // [16][128] this layer
     ushort_t* __restrict__ xW,             // [8][M][128] out, permuted rows
     float* __restrict__ stbl,              // [M][16] out
     int M) {
  __shared__ __align__(16) ushort_t wbuf[2][16384];   // 2 x 32 KB
  int tid = threadIdx.x, wv = tid >> 6, lane = tid & 63;
  int l15 = lane & 15, quad = lane >> 4;
  int node0 = blockIdx.x * 128 + wv * 32;

  // B-frags: 2 node tiles per wave, registers for all 8 relations + scores
  bf16x8 bx[2][4];
  #pragma unroll
  for (int tile = 0; tile < 2; tile++) {
    int node = node0 + tile * 16 + l15;
    int nc = node < M ? node : M - 1;
    if (F32IN) {
      const float* row = (const float*)Ain + (size_t)nc * 128;
      #pragma unroll
      for (int kb = 0; kb < 4; kb++) {
        float4 a = *(const float4*)(row + kb * 32 + quad * 8);
        float4 b = *(const float4*)(row + kb * 32 + quad * 8 + 4);
        union { bf16x8 v; ushort_t u[8]; } t;
        t.u[0] = fToBf(a.x); t.u[1] = fToBf(a.y); t.u[2] = fToBf(a.z); t.u[3] = fToBf(a.w);
        t.u[4] = fToBf(b.x); t.u[5] = fToBf(b.y); t.u[6] = fToBf(b.z); t.u[7] = fToBf(b.w);
        bx[tile][kb] = t.v;
      }
    } else {
      const ushort_t* row = (const ushort_t*)Ain + (size_t)nc * 128;
      #pragma unroll
      for (int kb = 0; kb < 4; kb++)
        bx[tile][kb] = *(const bf16x8*)(row + kb * 32 + quad * 8);
    }
  }

  // stage W[0] (flat 32 KB copy)
  #pragma unroll
  for (int i = 0; i < 8; i++)
    *(int4*)(wbuf[0] + (size_t)(tid + i * 256) * 8) =
        *(const int4*)(WTf + (size_t)(tid + i * 256) * 8);
  __syncthreads();

  for (int r = 0; r < 8; r++) {
    // prefetch W[r+1] into registers (hidden behind compute)
    int4 pf[8];
    if (r < 7) {
      const ushort_t* src = WTf + (size_t)(r + 1) * 16384;
      #pragma unroll
      for (int i = 0; i < 8; i++)
        pf[i] = *(const int4*)(src + (size_t)(tid + i * 256) * 8);
    }
    const ushort_t* wb = wbuf[r & 1];
    uint2 po[2][8];   // packed bf16 results: po[tile][mt] = ch mt*16+quad*4+[0..3]
    #pragma unroll
    for (int mt = 0; mt < 8; mt++) {
      f32x4 a0 = {}, a1 = {};
      #pragma unroll
      for (int kb = 0; kb < 4; kb++) {
        bf16x8 af = *(const bf16x8*)(wb + (size_t)((mt * 4 + kb) * 64 + lane) * 8);
        a0 = __builtin_amdgcn_mfma_f32_16x16x32_bf16(af, bx[0][kb], a0, 0, 0, 0);
        a1 = __builtin_amdgcn_mfma_f32_16x16x32_bf16(af, bx[1][kb], a1, 0, 0, 0);
      }
      po[0][mt].x = packBf(a0[0], a0[1]); po[0][mt].y = packBf(a0[2], a0[3]);
      po[1][mt].x = packBf(a1[0], a1[1]); po[1][mt].y = packBf(a1[2], a1[3]);
    }
    // permuted stores: lane covers bytes [quad*64, quad*64+64) of its node row
    #pragma unroll
    for (int tile = 0; tile < 2; tile++) {
      int node = node0 + tile * 16 + l15;
      if (node < M) {
        ushort_t* rowp = xW + ((size_t)r * M + node) * 128 + quad * 32;
        #pragma unroll
        for (int i = 0; i < 4; i++) {
          int4 v = {(int)po[tile][2 * i].x, (int)po[tile][2 * i].y,
                    (int)po[tile][2 * i + 1].x, (int)po[tile][2 * i + 1].y};
          *(int4*)(rowp + i * 8) = v;
        }
      }
    }
    // restage prefetched W[r+1]
    if (r < 7) {
      ushort_t* db = wbuf[(r + 1) & 1];
      #pragma unroll
      for (int i = 0; i < 8; i++)
        *(int4*)(db + (size_t)(tid + i * 256) * 8) = pf[i];
    }
    __syncthreads();
  }

  // score pass: stbl[node][0..7] = x.Wq[r], [8..15] = x.Wk[r]
  bf16x8 aq[4];
  #pragma unroll
  for (int kb = 0; kb < 4; kb++)
    aq[kb] = *(const bf16x8*)(Wqk + (size_t)l15 * 128 + kb * 32 + quad * 8);
  #pragma unroll
  for (int tile = 0; tile < 2; tile++) {
    f32x4 s = {};
    #pragma unroll
    for (int kb = 0; kb < 4; kb++)
      s = __builtin_amdgcn_mfma_f32_16x16x32_bf16(aq[kb], bx[tile][kb], s, 0, 0, 0);
    int node = node0 + tile * 16 + l15;
    if (node < M) {
      float4 v = {s[0], s[1], s[2], s[3]};
      *(float4*)(stbl + (size_t)node * 16 + quad * 4) = v;
    }
  }
}

// -------------------- fused softmax + weighted aggregation -----------------
// R2-proven gather (position-agnostic over permuted rows). Epilogue maps
// position p = fcol*8+i back to channel c = (fcol&3)*32 + (i>>2)*16 +
// (fcol>>2)*4 + (i&3) for bias/output (h written in STANDARD order).

#define ACC8(W_, V_)                                                     \
  acc[0] += W_ * bfToF((ushort_t)(V_.x & 0xFFFF));                       \
  acc[1] += W_ * bfToF((ushort_t)(V_.x >> 16));                          \
  acc[2] += W_ * bfToF((ushort_t)(V_.y & 0xFFFF));                       \
  acc[3] += W_ * bfToF((ushort_t)(V_.y >> 16));                          \
  acc[4] += W_ * bfToF((ushort_t)(V_.z & 0xFFFF));                       \
  acc[5] += W_ * bfToF((ushort_t)(V_.z >> 16));                          \
  acc[6] += W_ * bfToF((ushort_t)(V_.w & 0xFFFF));                       \
  acc[7] += W_ * bfToF((ushort_t)(V_.w >> 16));

__global__ __launch_bounds__(256) void
k_aggr(const ushort_t* __restrict__ feat,   // [R*N][128] bf16 (= xW, permuted)
       const float* __restrict__ stbl,      // [N][16]: 0..7 q-side, 8..15 k-side
       const int* __restrict__ rowptr, const int* __restrict__ sorted,
       const float* __restrict__ bias, ushort_t* __restrict__ outp, int n) {
  int tid = threadIdx.x, wv = tid >> 6, lane = tid & 63;
  int t = blockIdx.x * 4 + wv;
  if (t >= n) return;
  int e0 = rowptr[t], e1 = rowptr[t + 1];
  int g4 = lane >> 4, fcol = lane & 15;

  float m = -INFINITY, den = 0.f;
  float acc[8] = {};

  for (int base = e0; base < e1; base += 64) {
    int cnt = min(64, e1 - base);
    float alpha = -INFINITY;
    int pk = 0;
    if (lane < cnt) {
      pk = sorted[base + lane];
      int s = pk & 0xFFFF, r = pk >> 16;
      float a = stbl[(size_t)t * 16 + r] + stbl[(size_t)s * 16 + 8 + r];
      alpha = (a >= 0.f) ? a : 0.2f * a;   // leaky_relu 0.2
    }
    float cm = alpha;
    #pragma unroll
    for (int off = 32; off; off >>= 1) cm = fmaxf(cm, __shfl_xor(cm, off, 64));
    float nm = fmaxf(m, cm);
    float sc = __expf(m - nm);
    den *= sc;
    #pragma unroll
    for (int i = 0; i < 8; i++) acc[i] *= sc;
    float w = (lane < cnt) ? __expf(alpha - nm) : 0.f;
    float ws = w;
    #pragma unroll
    for (int off = 32; off; off >>= 1) ws += __shfl_xor(ws, off, 64);
    den += ws;
    m = nm;

    for (int g = 0; g < cnt; g += 16) {    // 16 edges/iter, 4 dwordx4 in flight
      int i0 = g + g4;
      float w0 = __shfl(w, i0, 64);
      float w1 = __shfl(w, i0 + 4, 64);
      float w2 = __shfl(w, i0 + 8, 64);
      float w3 = __shfl(w, i0 + 12, 64);
      int p0 = __shfl(pk, i0, 64);
      int p1 = __shfl(pk, i0 + 4, 64);
      int p2 = __shfl(pk, i0 + 8, 64);
      int p3 = __shfl(pk, i0 + 12, 64);
      const uint4* r0 = (const uint4*)(feat + (size_t)((p0 >> 16) * n + (p0 & 0xFFFF)) * 128) + fcol;
      const uint4* r1 = (const uint4*)(feat + (size_t)((p1 >> 16) * n + (p1 & 0xFFFF)) * 128) + fcol;
      const uint4* r2 = (const uint4*)(feat + (size_t)((p2 >> 16) * n + (p2 & 0xFFFF)) * 128) + fcol;
      const uint4* r3 = (const uint4*)(feat + (size_t)((p3 >> 16) * n + (p3 & 0xFFFF)) * 128) + fcol;
      uint4 v0 = *r0;
      uint4 v1 = *r1;
      uint4 v2 = *r2;
      uint4 v3 = *r3;
      ACC8(w0, v0)
      ACC8(w1, v1)
      ACC8(w2, v2)
      ACC8(w3, v3)
    }
  }

  #pragma unroll
  for (int i = 0; i < 8; i++) acc[i] += __shfl_xor(acc[i], 16, 64);
  #pragma unroll
  for (int i = 0; i < 8; i++) acc[i] += __shfl_xor(acc[i], 32, 64);

  float inv = (den > 0.f) ? 1.f / (den + 1e-16f) : 0.f;
  // un-permute: acc[0..3] -> channels base0+[0..3], acc[4..7] -> base0+16+[0..3]
  int base0 = (fcol & 3) * 32 + (fcol >> 2) * 4;
  float4 ba = *(const float4*)(bias + base0);
  float4 bb = *(const float4*)(bias + base0 + 16);
  uint2 oa, ob;
  oa.x = packBf(fmaxf(acc[0] * inv + ba.x, 0.f), fmaxf(acc[1] * inv + ba.y, 0.f));
  oa.y = packBf(fmaxf(acc[2] * inv + ba.z, 0.f), fmaxf(acc[3] * inv + ba.w, 0.f));
  ob.x = packBf(fmaxf(acc[4] * inv + bb.x, 0.f), fmaxf(acc[5] * inv + bb.y, 0.f));
  ob.y = packBf(fmaxf(acc[6] * inv + bb.z, 0.f), fmaxf(acc[7] * inv + bb.w, 0.f));
  if (lane < 16) {
    *(uint2*)(outp + (size_t)t * 128 + base0) = oa;
    *(uint2*)(outp + (size_t)t * 128 + base0 + 16) = ob;
  }
}

// ----------------------------- final linear --------------------------------

#define LDA 136

__global__ __launch_bounds__(256) void
k_gemmL(const ushort_t* __restrict__ A, const float* __restrict__ Wl,
        float* __restrict__ Cout, const float* __restrict__ bias, int M) {
  __shared__ ushort_t As[64 * LDA];
  __shared__ ushort_t Bs[128 * LDA];
  int tid = threadIdx.x;
  int row0 = blockIdx.x * 64;
  for (int c = tid; c < 1024; c += 256) {
    int r = c >> 4, off = (c & 15) * 8;
    int4 v = {0, 0, 0, 0};
    if (row0 + r < M) v = *(const int4*)(A + (size_t)(row0 + r) * 128 + off);
    *(int4*)(As + r * LDA + off) = v;
  }
  for (int c = tid; c < 2048; c += 256) {
    int nn = c >> 4, off = (c & 15) * 8;
    float4 a = *(const float4*)(Wl + (size_t)nn * 128 + off);
    float4 b = *(const float4*)(Wl + (size_t)nn * 128 + off + 4);
    ushort_t* d = Bs + nn * LDA + off;
    d[0] = fToBf(a.x); d[1] = fToBf(a.y); d[2] = fToBf(a.z); d[3] = fToBf(a.w);
    d[4] = fToBf(b.x); d[5] = fToBf(b.y); d[6] = fToBf(b.z); d[7] = fToBf(b.w);
  }
  __syncthreads();
  int wv = tid >> 6, lane = tid & 63;
  int l15 = lane & 15, quad = lane >> 4;
  int wr = wv * 16;
  bf16x8 afr[4];
  #pragma unroll
  for (int kb = 0; kb < 4; kb++)
    afr[kb] = *reinterpret_cast<const bf16x8*>(As + (wr + l15) * LDA + kb * 32 + quad * 8);
  f32x4 acc[8] = {};
  #pragma unroll
  for (int ct = 0; ct < 8; ct++)
    #pragma unroll
    for (int kb = 0; kb < 4; kb++) {
      bf16x8 bfr = *reinterpret_cast<const bf16x8*>(Bs + (ct * 16 + l15) * LDA + kb * 32 + quad * 8);
      acc[ct] = __builtin_amdgcn_mfma_f32_16x16x32_bf16(afr[kb], bfr, acc[ct], 0, 0, 0);
    }
  #pragma unroll
  for (int ct = 0; ct < 8; ct++)
    #pragma unroll
    for (int reg = 0; reg < 4; reg++) {
      int rr = row0 + wr + quad * 4 + reg;
      if (rr < M) Cout[(size_t)rr * 128 + ct * 16 + l15] = acc[ct][reg] + bias[ct * 16 + l15];
    }
}

// ------------------------------- launcher ----------------------------------

extern "C" void kernel_launch(void* const* d_in, const int* in_sizes, int n_in,
                              void* d_out, int out_size, void* d_ws, size_t ws_size,
                              hipStream_t stream) {
  const float* x   = (const float*)d_in[0];
  const int* ei    = (const int*)d_in[1];
  const int* etype = (const int*)d_in[2];
  const float* W1  = (const float*)d_in[4];
  const float* q1  = (const float*)d_in[5];
  const float* k1  = (const float*)d_in[6];
  const float* b1  = (const float*)d_in[7];
  const float* W2  = (const float*)d_in[8];
  const float* q2  = (const float*)d_in[9];
  const float* k2  = (const float*)d_in[10];
  const float* b2  = (const float*)d_in[11];
  const float* Wl  = (const float*)d_in[12];
  const float* bl  = (const float*)d_in[13];
  float* out       = (float*)d_out;

  const int N = in_sizes[0] / 128;   // 50000
  const int E = in_sizes[2];         // 800000

  char* ws = (char*)d_ws;
  size_t off = 0;
  auto alloc = [&](size_t bytes) {
    size_t o = off;
    off = (off + bytes + 255) & ~(size_t)255;
    return o;
  };

  ushort_t* xW    = (ushort_t*)(ws + alloc((size_t)8 * N * 128 * 2));
  ushort_t* h1    = (ushort_t*)(ws + alloc((size_t)N * 128 * 2));
  ushort_t* h2    = (ushort_t*)(ws + alloc((size_t)N * 128 * 2));
  ushort_t* WTf   = (ushort_t*)(ws + alloc((size_t)2 * 8 * 16384 * 2));
  ushort_t* wqk   = (ushort_t*)(ws + alloc(2 * 16 * 128 * 2));
  float* stblA    = (float*)(ws + alloc((size_t)N * 16 * 4));
  float* stblB    = (float*)(ws + alloc((size_t)N * 16 * 4));
  int* deg        = (int*)(ws + alloc((size_t)N * 4));
  int* cursor     = (int*)(ws + alloc((size_t)N * 4));
  int* incl       = (int*)(ws + alloc((size_t)N * 4));
  int* rowptr     = (int*)(ws + alloc((size_t)(N + 1) * 4));
  int* bsum       = (int*)(ws + alloc(256 * 4));
  int* sorted     = (int*)(ws + alloc((size_t)E * 4));
  (void)ws_size; (void)n_in; (void)out_size;

  const int* srcp = ei;
  const int* tgtp = ei + E;

  int gE = (E + 255) / 256;
  int gN = (N + 255) / 256;
  int gW = (N + 3) / 4;          // k_aggr
  int gX = (N + 127) / 128;      // k_xw: 391
  int gL = (N + 63) / 64;        // k_gemmL: 782

  // CSR build (once; same graph both layers)
  hipMemsetAsync(deg, 0, (size_t)N * 4, stream);
  hipMemsetAsync(cursor, 0, (size_t)N * 4, stream);
  k_count<<<gE, 256, 0, stream>>>(tgtp, deg, E);
  k_scanA<<<gN, 256, 0, stream>>>(deg, incl, bsum, N);
  k_scanB<<<1, 256, 0, stream>>>(bsum, gN);
  k_scanC<<<gN, 256, 0, stream>>>(deg, incl, bsum, rowptr, N, E);
  k_scatter<<<gE, 256, 0, stream>>>(srcp, tgtp, etype, rowptr, cursor, sorted, E);

  // weight prep (both layers)
  k_wTf<<<128, 256, 0, stream>>>(W1, W2, WTf);
  k_wqwk<<<16, 256, 0, stream>>>(W1, q1, k1, W2, q2, k2, wqk);

  // layer 1 (reads f32 x directly; emits xW + stblA)
  k_xw<true><<<gX, 256, 0, stream>>>(x, WTf, wqk, xW, stblA, N);
  k_aggr<<<gW, 256, 0, stream>>>(xW, stblA, rowptr, sorted, b1, h1, N);

  // layer 2
  k_xw<false><<<gX, 256, 0, stream>>>(h1, WTf + (size_t)8 * 16384,
                                      wqk + 2048, xW, stblB, N);
  k_aggr<<<gW, 256, 0, stream>>>(xW, stblB, rowptr, sorted, b2, h2, N);

  // final linear
  k_gemmL<<<gL, 256, 0, stream>>>(h2, Wl, out, bl, N);
}